// Round 1
// baseline (568.834 us; speedup 1.0000x reference)
//
#include <hip/hip_runtime.h>
#include <hip/hip_bf16.h>
#include <stdint.h>

// Fused causal self-attention block: qkv GEMM -> flash attention -> proj GEMM.
// B=4 T=2048 E=1024 H=16 HD=64. All GEMM/attn matmuls in bf16 MFMA
// (mfma_f32_16x16x32_bf16), fp32 accumulate. Validation threshold 2.27e-2
// permits bf16.

#define B_  4
#define T_  2048
#define E_  1024
#define H_  16
#define HD_ 64

typedef unsigned short u16;
typedef __bf16 bf16x8 __attribute__((ext_vector_type(8)));
typedef float f32x4 __attribute__((ext_vector_type(4)));

struct alignas(8) us4 { u16 x, y, z, w; };

__device__ __forceinline__ u16 tobf(float f) {
  union { float f; uint32_t u; } x; x.f = f;
  uint32_t r = (x.u + 0x7FFF + ((x.u >> 16) & 1)) >> 16;  // RNE
  return (u16)r;
}

__device__ __forceinline__ void gload_lds16(const void* g, void* l) {
  // global -> LDS direct, 16B per lane. LDS dest is wave-uniform base +
  // lane*16 (guide §5); addrspace cast via uintptr (CK pattern).
  auto gp = reinterpret_cast<const __attribute__((address_space(1))) uint32_t*>(
      reinterpret_cast<uintptr_t>(g));
  auto lp = reinterpret_cast<__attribute__((address_space(3))) uint32_t*>(
      reinterpret_cast<uintptr_t>(l));
  __builtin_amdgcn_global_load_lds(gp, lp, 16, 0, 0);
}

__device__ __forceinline__ bf16x8 ld_frag(const u16* p) {
  return *reinterpret_cast<const bf16x8*>(p);
}

// ---------------- conversion kernels ----------------

__global__ void cvt_bf16_kernel(const float* __restrict__ in, u16* __restrict__ out, int n) {
  int i = (blockIdx.x * blockDim.x + threadIdx.x) * 4;
  if (i >= n) return;
  float4 v = *reinterpret_cast<const float4*>(in + i);
  us4 o = { tobf(v.x), tobf(v.y), tobf(v.z), tobf(v.w) };
  *reinterpret_cast<us4*>(out + i) = o;
}

// in: [K][N] f32 row-major -> out: [N][K] bf16 (B^T layout for GEMM)
__global__ void transpose_cvt_kernel(const float* __restrict__ in, u16* __restrict__ out,
                                     int K, int N) {
  __shared__ u16 tile[32][33];
  int n0 = blockIdx.x * 32, k0 = blockIdx.y * 32;
  int tx = threadIdx.x, ty = threadIdx.y;  // (32,8)
#pragma unroll
  for (int i = 0; i < 32; i += 8)
    tile[ty + i][tx] = tobf(in[(size_t)(k0 + ty + i) * N + n0 + tx]);
  __syncthreads();
#pragma unroll
  for (int i = 0; i < 32; i += 8)
    out[(size_t)(n0 + ty + i) * K + k0 + tx] = tile[tx][ty + i];
}

// ---------------- GEMM (m97-style 128x128 tile, BK=32) ----------------
// A: [M][1024] bf16 row-major.  Bt: [N][1024] bf16 (B transposed).
// MODE 0: qkv epilogue (bias, q*0.125, scatter q/k [B,H,T,HD], v^T [B,H,HD,T])
// MODE 1: proj epilogue (bias, fp32 out)

template <int MODE>
__launch_bounds__(256)
__global__ void gemm_kernel(const u16* __restrict__ A, const u16* __restrict__ Bt,
                            const float* __restrict__ bias,
                            u16* __restrict__ qws, u16* __restrict__ kws,
                            u16* __restrict__ vtws, float* __restrict__ out) {
  constexpr int K = 1024, BK = 32;
  __shared__ u16 As[128 * BK];
  __shared__ u16 Bs[128 * BK];
  const int tid = threadIdx.x;
  const int wid = tid >> 6, lane = tid & 63;
  const int wm = wid >> 1, wn = wid & 1;  // 2x2 wave grid, 64x64 per wave
  const int row0 = blockIdx.x * 128, col0 = blockIdx.y * 128;

  f32x4 acc[4][4] = {};

  const int sr = lane >> 2;        // staging sub-row within 16-row chunk
  const int sc = (lane & 3) * 8;   // staging element offset within row (8 bf16 = 16B)
  const int lrow = lane & 15;      // fragment row/col
  const int lkb = (lane >> 4) * 8; // fragment k-offset (elements)

  for (int k0 = 0; k0 < K; k0 += BK) {
#pragma unroll
    for (int c = 0; c < 2; ++c) {
      int chunk = wid * 2 + c;  // 0..7, 16 rows each
      int r = chunk * 16 + sr;
      gload_lds16(A + (size_t)(row0 + r) * K + k0 + sc, &As[chunk * 512]);
      gload_lds16(Bt + (size_t)(col0 + r) * K + k0 + sc, &Bs[chunk * 512]);
    }
    __syncthreads();
    bf16x8 af[4], bf[4];
#pragma unroll
    for (int i = 0; i < 4; ++i) {
      af[i] = ld_frag(&As[(wm * 64 + i * 16 + lrow) * BK + lkb]);
      bf[i] = ld_frag(&Bs[(wn * 64 + i * 16 + lrow) * BK + lkb]);
    }
#pragma unroll
    for (int i = 0; i < 4; ++i)
#pragma unroll
      for (int j = 0; j < 4; ++j)
        acc[i][j] = __builtin_amdgcn_mfma_f32_16x16x32_bf16(af[i], bf[j], acc[i][j], 0, 0, 0);
    __syncthreads();
  }

  // C/D layout (guide §3, m89-verified): col = lane&15, row = (lane>>4)*4 + reg
#pragma unroll
  for (int mi = 0; mi < 4; ++mi) {
#pragma unroll
    for (int ni = 0; ni < 4; ++ni) {
      const int gr0 = row0 + wm * 64 + mi * 16 + (lane >> 4) * 4;
      const int gc = col0 + wn * 64 + ni * 16 + (lane & 15);
      const float bv = bias[gc];
      f32x4 v = acc[mi][ni];
      if constexpr (MODE == 0) {
        const int part = gc >> 10;          // 0=q 1=k 2=v
        const int e = gc & 1023;
        const int h = e >> 6, d = e & 63;
#pragma unroll
        for (int r = 0; r < 4; ++r) {
          const int m = gr0 + r;
          const int b = m >> 11, t = m & 2047;
          const float val = v[r] + bv;
          const size_t bh = (size_t)(b * H_ + h);
          if (part == 0)
            qws[(bh * T_ + t) * HD_ + d] = tobf(val * 0.125f);  // fold 1/sqrt(64)
          else if (part == 1)
            kws[(bh * T_ + t) * HD_ + d] = tobf(val);
          else
            vtws[(bh * HD_ + d) * T_ + t] = tobf(val);          // V transposed
        }
      } else {
#pragma unroll
        for (int r = 0; r < 4; ++r) {
          const int m = gr0 + r;
          out[(size_t)m * E_ + gc] = v[r] + bv;
        }
      }
    }
  }
}

// ---------------- flash attention ----------------
// grid = B*H*(T/64); block = 256 (4 waves). Wave w owns 16 Q rows.
// Q in regs; K,V read from global (L2-resident, 256KB/head). KV blocks of 32.
// Online softmax per row, wave-parallel via shfl_xor width-16.

__launch_bounds__(256)
__global__ void attn_kernel(const u16* __restrict__ q, const u16* __restrict__ k,
                            const u16* __restrict__ vt, u16* __restrict__ y) {
  __shared__ u16 pt[4][16][40];  // per-wave P tile, padded 32->40 to break bank conflicts
  const int bid = blockIdx.x;
  const int bh = bid >> 5, qt = bid & 31;  // T/64 = 32 q-tiles
  const int tid = threadIdx.x, w = tid >> 6, lane = tid & 63;
  const int qb = qt * 64 + w * 16;  // this wave's first Q row
  const u16* qp = q + (size_t)bh * T_ * HD_;
  const u16* kp = k + (size_t)bh * T_ * HD_;
  const u16* vp = vt + (size_t)bh * HD_ * T_;
  const int lc = lane & 15, lk = lane >> 4;

  bf16x8 aq[2];
  aq[0] = ld_frag(qp + (qb + lc) * HD_ + lk * 8);
  aq[1] = ld_frag(qp + (qb + lc) * HD_ + 32 + lk * 8);

  f32x4 o[4] = {};
  float mr[4], lr[4];
#pragma unroll
  for (int r = 0; r < 4; ++r) { mr[r] = -1e30f; lr[r] = 0.f; }

  for (int kv0 = 0; kv0 < qb + 16; kv0 += 32) {
    // S = Q K^T  (16 q-rows x 32 kv-cols), 2 n-frags x 2 k-steps
    f32x4 s[2] = {};
#pragma unroll
    for (int n = 0; n < 2; ++n) {
      bf16x8 b0 = ld_frag(kp + (size_t)(kv0 + n * 16 + lc) * HD_ + lk * 8);
      bf16x8 b1 = ld_frag(kp + (size_t)(kv0 + n * 16 + lc) * HD_ + 32 + lk * 8);
      s[n] = __builtin_amdgcn_mfma_f32_16x16x32_bf16(aq[0], b0, s[n], 0, 0, 0);
      s[n] = __builtin_amdgcn_mfma_f32_16x16x32_bf16(aq[1], b1, s[n], 0, 0, 0);
    }
    // causal mask (only blocks crossing the diagonal)
    if (kv0 + 31 > qb) {
#pragma unroll
      for (int n = 0; n < 2; ++n) {
        const int kv = kv0 + n * 16 + lc;
#pragma unroll
        for (int r = 0; r < 4; ++r)
          if (kv > qb + lk * 4 + r) s[n][r] = -1e30f;
      }
    }
    // online softmax: row stats live in the 16-lane group (cols = lane&15)
    float pm[4], al[4], rs[4];
#pragma unroll
    for (int r = 0; r < 4; ++r) {
      pm[r] = fmaxf(s[0][r], s[1][r]);
#pragma unroll
      for (int off = 1; off < 16; off <<= 1)
        pm[r] = fmaxf(pm[r], __shfl_xor(pm[r], off, 16));
      const float mn = fmaxf(mr[r], pm[r]);
      al[r] = __expf(mr[r] - mn);
      mr[r] = mn;
      rs[r] = 0.f;
    }
#pragma unroll
    for (int n = 0; n < 2; ++n)
#pragma unroll
      for (int r = 0; r < 4; ++r) {
        const float p = __expf(s[n][r] - mr[r]);
        s[n][r] = p;
        rs[r] += p;
      }
#pragma unroll
    for (int r = 0; r < 4; ++r) {
#pragma unroll
      for (int off = 1; off < 16; off <<= 1)
        rs[r] += __shfl_xor(rs[r], off, 16);
      lr[r] = lr[r] * al[r] + rs[r];
    }
#pragma unroll
    for (int n = 0; n < 4; ++n)
#pragma unroll
      for (int r = 0; r < 4; ++r)
        o[n][r] *= al[r];
    // P (C-layout) -> LDS -> A-layout fragment. Per-wave region, no barrier;
    // compiler orders ds_write/ds_read via lgkmcnt (same LDS object).
#pragma unroll
    for (int n = 0; n < 2; ++n)
#pragma unroll
      for (int r = 0; r < 4; ++r)
        pt[w][lk * 4 + r][n * 16 + lc] = tobf(s[n][r]);
    const bf16x8 pa = ld_frag(&pt[w][lc][lk * 8]);
    // O += P V : B-operand from V^T (8 contiguous kv per lane)
#pragma unroll
    for (int n = 0; n < 4; ++n) {
      bf16x8 bvf = ld_frag(vp + (size_t)(n * 16 + lc) * T_ + kv0 + lk * 8);
      o[n] = __builtin_amdgcn_mfma_f32_16x16x32_bf16(pa, bvf, o[n], 0, 0, 0);
    }
  }

  const int b = bh >> 4, h = bh & 15;
#pragma unroll
  for (int n = 0; n < 4; ++n)
#pragma unroll
    for (int r = 0; r < 4; ++r) {
      const int t = qb + lk * 4 + r;
      const int d = n * 16 + lc;
      y[((size_t)b * T_ + t) * E_ + h * HD_ + d] = tobf(o[n][r] / lr[r]);
    }
}

// ---------------- launch ----------------

extern "C" void kernel_launch(void* const* d_in, const int* in_sizes, int n_in,
                              void* d_out, int out_size, void* d_ws, size_t ws_size,
                              hipStream_t stream) {
  const float* x  = (const float*)d_in[0];
  const float* Wa = (const float*)d_in[1];
  const float* ba = (const float*)d_in[2];
  const float* Wp = (const float*)d_in[3];
  const float* bp = (const float*)d_in[4];
  float* out = (float*)d_out;

  // workspace layout (u16 units). y aliases xb (x dead after GEMM1). 72MB total.
  u16* ws   = (u16*)d_ws;
  u16* xb   = ws;                                  // 8M  (x bf16; later y bf16)
  u16* waT  = xb  + (size_t)8 * 1024 * 1024;       // 3M  (W_attn^T bf16)
  u16* wpT  = waT + (size_t)3 * 1024 * 1024;       // 1M  (W_proj^T bf16)
  u16* qws  = wpT + (size_t)1024 * 1024;           // 8M  q [B,H,T,HD]
  u16* kws  = qws + (size_t)8 * 1024 * 1024;       // 8M  k [B,H,T,HD]
  u16* vtws = kws + (size_t)8 * 1024 * 1024;       // 8M  v^T [B,H,HD,T]
  u16* yws  = xb;                                  // alias

  cvt_bf16_kernel<<<dim3(8192), dim3(256), 0, stream>>>(x, xb, 8 * 1024 * 1024);
  transpose_cvt_kernel<<<dim3(96, 32), dim3(32, 8), 0, stream>>>(Wa, waT, 1024, 3072);
  transpose_cvt_kernel<<<dim3(32, 32), dim3(32, 8), 0, stream>>>(Wp, wpT, 1024, 1024);

  gemm_kernel<0><<<dim3(64, 24), dim3(256), 0, stream>>>(xb, waT, ba, qws, kws, vtws, nullptr);
  attn_kernel<<<dim3(2048), dim3(256), 0, stream>>>(qws, kws, vtws, yws);
  gemm_kernel<1><<<dim3(64, 8), dim3(256), 0, stream>>>(yws, wpT, bp, nullptr, nullptr, nullptr, out);
}

// Round 2
// 354.822 us; speedup vs baseline: 1.6032x; 1.6032x over previous
//
#include <hip/hip_runtime.h>
#include <hip/hip_bf16.h>
#include <stdint.h>

// Fused causal self-attention block: qkv GEMM -> flash attention -> proj GEMM.
// B=4 T=2048 E=1024 H=16 HD=64. All GEMM/attn matmuls in bf16 MFMA
// (mfma_f32_16x16x32_bf16), fp32 accumulate.

#define B_  4
#define T_  2048
#define E_  1024
#define H_  16
#define HD_ 64

typedef unsigned short u16;
typedef __bf16 bf16x8 __attribute__((ext_vector_type(8)));
typedef float f32x4 __attribute__((ext_vector_type(4)));

struct alignas(8) us4 { u16 x, y, z, w; };

__device__ __forceinline__ u16 tobf(float f) {
  union { float f; uint32_t u; } x; x.f = f;
  uint32_t r = (x.u + 0x7FFF + ((x.u >> 16) & 1)) >> 16;  // RNE
  return (u16)r;
}

__device__ __forceinline__ void gload_lds16(const void* g, void* l) {
  // global -> LDS direct, 16B per lane (wave-uniform LDS base + lane*16).
  auto gp = reinterpret_cast<const __attribute__((address_space(1))) uint32_t*>(
      reinterpret_cast<uintptr_t>(g));
  auto lp = reinterpret_cast<__attribute__((address_space(3))) uint32_t*>(
      reinterpret_cast<uintptr_t>(l));
  __builtin_amdgcn_global_load_lds(gp, lp, 16, 0, 0);
}

__device__ __forceinline__ bf16x8 ld_frag(const u16* p) {
  return *reinterpret_cast<const bf16x8*>(p);
}

// DPP-based 16-lane all-reduce (pure VALU: quad_perm xor1, xor2, row_ror 4, 8)
#define DPPF(x, ctrl) __uint_as_float((unsigned)__builtin_amdgcn_update_dpp( \
    (int)__float_as_uint(x), (int)__float_as_uint(x), (ctrl), 0xF, 0xF, true))

__device__ __forceinline__ float rmax16(float x) {
  x = fmaxf(x, DPPF(x, 0xB1));   // quad_perm(1,0,3,2)  xor 1
  x = fmaxf(x, DPPF(x, 0x4E));   // quad_perm(2,3,0,1)  xor 2
  x = fmaxf(x, DPPF(x, 0x124));  // row_ror:4
  x = fmaxf(x, DPPF(x, 0x128));  // row_ror:8
  return x;
}
__device__ __forceinline__ float rsum16(float x) {
  x += DPPF(x, 0xB1);
  x += DPPF(x, 0x4E);
  x += DPPF(x, 0x124);
  x += DPPF(x, 0x128);
  return x;
}

// ---------------- conversion kernels ----------------

__global__ void cvt_bf16_kernel(const float* __restrict__ in, u16* __restrict__ out, int n) {
  int i = (blockIdx.x * blockDim.x + threadIdx.x) * 4;
  if (i >= n) return;
  float4 v = *reinterpret_cast<const float4*>(in + i);
  us4 o = { tobf(v.x), tobf(v.y), tobf(v.z), tobf(v.w) };
  *reinterpret_cast<us4*>(out + i) = o;
}

// in: [K][N] f32 row-major -> out: [N][K] bf16 (B^T layout for GEMM)
__global__ void transpose_cvt_kernel(const float* __restrict__ in, u16* __restrict__ out,
                                     int K, int N) {
  __shared__ u16 tile[32][33];
  int n0 = blockIdx.x * 32, k0 = blockIdx.y * 32;
  int tx = threadIdx.x, ty = threadIdx.y;  // (32,8)
#pragma unroll
  for (int i = 0; i < 32; i += 8)
    tile[ty + i][tx] = tobf(in[(size_t)(k0 + ty + i) * N + n0 + tx]);
  __syncthreads();
#pragma unroll
  for (int i = 0; i < 32; i += 8)
    out[(size_t)(n0 + ty + i) * K + k0 + tx] = tile[tx][ty + i];
}

// ---------------- GEMM (m97-style 128x128 tile, BK=32) ----------------

template <int MODE>
__launch_bounds__(256)
__global__ void gemm_kernel(const u16* __restrict__ A, const u16* __restrict__ Bt,
                            const float* __restrict__ bias,
                            u16* __restrict__ qws, u16* __restrict__ kws,
                            u16* __restrict__ vtws, float* __restrict__ out) {
  constexpr int K = 1024, BK = 32;
  __shared__ u16 As[128 * BK];
  __shared__ u16 Bs[128 * BK];
  const int tid = threadIdx.x;
  const int wid = tid >> 6, lane = tid & 63;
  const int wm = wid >> 1, wn = wid & 1;  // 2x2 wave grid, 64x64 per wave
  const int row0 = blockIdx.x * 128, col0 = blockIdx.y * 128;

  f32x4 acc[4][4] = {};

  const int sr = lane >> 2;
  const int sc = (lane & 3) * 8;
  const int lrow = lane & 15;
  const int lkb = (lane >> 4) * 8;

  for (int k0 = 0; k0 < K; k0 += BK) {
#pragma unroll
    for (int c = 0; c < 2; ++c) {
      int chunk = wid * 2 + c;
      int r = chunk * 16 + sr;
      gload_lds16(A + (size_t)(row0 + r) * K + k0 + sc, &As[chunk * 512]);
      gload_lds16(Bt + (size_t)(col0 + r) * K + k0 + sc, &Bs[chunk * 512]);
    }
    __syncthreads();
    bf16x8 af[4], bf[4];
#pragma unroll
    for (int i = 0; i < 4; ++i) {
      af[i] = ld_frag(&As[(wm * 64 + i * 16 + lrow) * BK + lkb]);
      bf[i] = ld_frag(&Bs[(wn * 64 + i * 16 + lrow) * BK + lkb]);
    }
#pragma unroll
    for (int i = 0; i < 4; ++i)
#pragma unroll
      for (int j = 0; j < 4; ++j)
        acc[i][j] = __builtin_amdgcn_mfma_f32_16x16x32_bf16(af[i], bf[j], acc[i][j], 0, 0, 0);
    __syncthreads();
  }

  // C/D layout: col = lane&15, row = (lane>>4)*4 + reg
#pragma unroll
  for (int mi = 0; mi < 4; ++mi) {
#pragma unroll
    for (int ni = 0; ni < 4; ++ni) {
      const int gr0 = row0 + wm * 64 + mi * 16 + (lane >> 4) * 4;
      const int gc = col0 + wn * 64 + ni * 16 + (lane & 15);
      const float bv = bias[gc];
      f32x4 v = acc[mi][ni];
      if constexpr (MODE == 0) {
        const int part = gc >> 10;          // 0=q 1=k 2=v
        const int e = gc & 1023;
        const int h = e >> 6, d = e & 63;
#pragma unroll
        for (int r = 0; r < 4; ++r) {
          const int m = gr0 + r;
          const int b = m >> 11, t = m & 2047;
          const float val = v[r] + bv;
          const size_t bh = (size_t)(b * H_ + h);
          if (part == 0)
            qws[(bh * T_ + t) * HD_ + d] = tobf(val * 0.125f);  // fold 1/sqrt(64)
          else if (part == 1)
            kws[(bh * T_ + t) * HD_ + d] = tobf(val);
          else
            vtws[(bh * HD_ + d) * T_ + t] = tobf(val);          // V transposed
        }
      } else {
#pragma unroll
        for (int r = 0; r < 4; ++r) {
          const int m = gr0 + r;
          out[(size_t)m * E_ + gc] = v[r] + bv;
        }
      }
    }
  }
}

// ---------------- flash attention ----------------
// grid = 1024 blocks x 4 waves. Each wave owns TWO mirrored 16-row granules
// (g and 127-g) so per-wave work is constant (~33 KV64-iterations) regardless
// of block->CU mapping. KV blocks of 64 (16 MFMA per softmax chain). K/V read
// from global (L2-resident). Softmax reduces via DPP (pure VALU).

__launch_bounds__(256, 4)
__global__ void attn_kernel(const u16* __restrict__ q, const u16* __restrict__ k,
                            const u16* __restrict__ vt, u16* __restrict__ y) {
  __shared__ u16 pt[4][16][72];  // per-wave P tile (16 q-rows x 64 kv, padded)
  const int tid = threadIdx.x, w = tid >> 6, lane = tid & 63;
  const int bh = blockIdx.x >> 4, blk = blockIdx.x & 15;
  const int pg = blk * 4 + w;              // 0..63: granule pair id
  const u16* qp = q + (size_t)bh * T_ * HD_;
  const u16* kp = k + (size_t)bh * T_ * HD_;
  const u16* vp = vt + (size_t)bh * HD_ * T_;
  const int b = bh >> 4, h = bh & 15;
  u16* yb = y + (size_t)b * T_ * E_ + h * HD_;
  u16* ptw = &pt[w][0][0];
  const int lc = lane & 15, lk = lane >> 4;

#pragma unroll
  for (int ph = 0; ph < 2; ++ph) {
    const int g = ph ? (127 - pg) : pg;    // mirrored pair -> constant work
    const int qb = g * 16;

    const bf16x8 aq0 = ld_frag(qp + (size_t)(qb + lc) * HD_ + lk * 8);
    const bf16x8 aq1 = ld_frag(qp + (size_t)(qb + lc) * HD_ + 32 + lk * 8);

    f32x4 o[4] = {};
    float mr[4], lr[4];
#pragma unroll
    for (int r = 0; r < 4; ++r) { mr[r] = -1e30f; lr[r] = 0.f; }

    for (int kv0 = 0; kv0 < qb + 16; kv0 += 64) {
      // S = Q K^T : 16 q-rows x 64 kv-cols
      f32x4 s[4] = {};
#pragma unroll
      for (int n = 0; n < 4; ++n) {
        const bf16x8 b0 = ld_frag(kp + (size_t)(kv0 + n * 16 + lc) * HD_ + lk * 8);
        const bf16x8 b1 = ld_frag(kp + (size_t)(kv0 + n * 16 + lc) * HD_ + 32 + lk * 8);
        s[n] = __builtin_amdgcn_mfma_f32_16x16x32_bf16(aq0, b0, s[n], 0, 0, 0);
        s[n] = __builtin_amdgcn_mfma_f32_16x16x32_bf16(aq1, b1, s[n], 0, 0, 0);
      }
      // hoist V loads so their latency hides under softmax
      bf16x8 vf[4][2];
#pragma unroll
      for (int n = 0; n < 4; ++n)
#pragma unroll
        for (int hh = 0; hh < 2; ++hh)
          vf[n][hh] = ld_frag(vp + (size_t)(n * 16 + lc) * T_ + kv0 + hh * 32 + lk * 8);

      // causal mask (only blocks crossing the diagonal)
      if (kv0 + 63 > qb) {
#pragma unroll
        for (int n = 0; n < 4; ++n) {
          const int kv = kv0 + n * 16 + lc;
#pragma unroll
          for (int r = 0; r < 4; ++r)
            if (kv > qb + lk * 4 + r) s[n][r] = -1e30f;
        }
      }
      // online softmax; row r lives on the 16-lane group (cols = lane&15)
      float al[4];
#pragma unroll
      for (int r = 0; r < 4; ++r) {
        float pm = fmaxf(fmaxf(s[0][r], s[1][r]), fmaxf(s[2][r], s[3][r]));
        pm = rmax16(pm);
        const float mn = fmaxf(mr[r], pm);
        al[r] = __expf(mr[r] - mn);
        mr[r] = mn;
      }
      float rs[4] = {0.f, 0.f, 0.f, 0.f};
#pragma unroll
      for (int n = 0; n < 4; ++n)
#pragma unroll
        for (int r = 0; r < 4; ++r) {
          const float p = __expf(s[n][r] - mr[r]);
          s[n][r] = p;
          rs[r] += p;
        }
#pragma unroll
      for (int r = 0; r < 4; ++r) {
        rs[r] = rsum16(rs[r]);
        lr[r] = lr[r] * al[r] + rs[r];
      }
#pragma unroll
      for (int n = 0; n < 4; ++n)
#pragma unroll
        for (int r = 0; r < 4; ++r)
          o[n][r] *= al[r];
      // P (C-layout) -> LDS -> A-layout fragments (per-wave region, no barrier)
#pragma unroll
      for (int n = 0; n < 4; ++n)
#pragma unroll
        for (int r = 0; r < 4; ++r)
          pt[w][lk * 4 + r][n * 16 + lc] = tobf(s[n][r]);
      const bf16x8 pa0 = ld_frag(&ptw[lc * 72 + lk * 8]);
      const bf16x8 pa1 = ld_frag(&ptw[lc * 72 + 32 + lk * 8]);
      // O += P V
#pragma unroll
      for (int n = 0; n < 4; ++n) {
        o[n] = __builtin_amdgcn_mfma_f32_16x16x32_bf16(pa0, vf[n][0], o[n], 0, 0, 0);
        o[n] = __builtin_amdgcn_mfma_f32_16x16x32_bf16(pa1, vf[n][1], o[n], 0, 0, 0);
      }
    }

    float invl[4];
#pragma unroll
    for (int r = 0; r < 4; ++r) invl[r] = 1.f / lr[r];
#pragma unroll
    for (int n = 0; n < 4; ++n)
#pragma unroll
      for (int r = 0; r < 4; ++r) {
        const int t = qb + lk * 4 + r;
        yb[(size_t)t * E_ + n * 16 + lc] = tobf(o[n][r] * invl[r]);
      }
  }
}

// ---------------- launch ----------------

extern "C" void kernel_launch(void* const* d_in, const int* in_sizes, int n_in,
                              void* d_out, int out_size, void* d_ws, size_t ws_size,
                              hipStream_t stream) {
  const float* x  = (const float*)d_in[0];
  const float* Wa = (const float*)d_in[1];
  const float* ba = (const float*)d_in[2];
  const float* Wp = (const float*)d_in[3];
  const float* bp = (const float*)d_in[4];
  float* out = (float*)d_out;

  u16* ws   = (u16*)d_ws;
  u16* xb   = ws;                                  // 8M  (x bf16; later y bf16)
  u16* waT  = xb  + (size_t)8 * 1024 * 1024;       // 3M  (W_attn^T bf16)
  u16* wpT  = waT + (size_t)3 * 1024 * 1024;       // 1M  (W_proj^T bf16)
  u16* qws  = wpT + (size_t)1024 * 1024;           // 8M  q [B,H,T,HD]
  u16* kws  = qws + (size_t)8 * 1024 * 1024;       // 8M  k [B,H,T,HD]
  u16* vtws = kws + (size_t)8 * 1024 * 1024;       // 8M  v^T [B,H,HD,T]
  u16* yws  = xb;                                  // alias

  cvt_bf16_kernel<<<dim3(8192), dim3(256), 0, stream>>>(x, xb, 8 * 1024 * 1024);
  transpose_cvt_kernel<<<dim3(96, 32), dim3(32, 8), 0, stream>>>(Wa, waT, 1024, 3072);
  transpose_cvt_kernel<<<dim3(32, 32), dim3(32, 8), 0, stream>>>(Wp, wpT, 1024, 1024);

  gemm_kernel<0><<<dim3(64, 24), dim3(256), 0, stream>>>(xb, waT, ba, qws, kws, vtws, nullptr);
  attn_kernel<<<dim3(1024), dim3(256), 0, stream>>>(qws, kws, vtws, yws);
  gemm_kernel<1><<<dim3(64, 8), dim3(256), 0, stream>>>(yws, wpT, bp, nullptr, nullptr, nullptr, out);
}